// Round 10
// baseline (228.766 us; speedup 1.0000x reference)
//
#include <hip/hip_runtime.h>
#include <hip/hip_bf16.h>
#include <stdint.h>

#define T_SEQ 4096
#define DIMX 1024
#define NH 16
#define HD 64
#define DLAT 256

typedef __bf16 bf16x8 __attribute__((ext_vector_type(8)));
typedef float floatx4 __attribute__((ext_vector_type(4)));

#define MFMA(a, b, c) __builtin_amdgcn_mfma_f32_16x16x32_bf16(a, b, c, 0, 0, 0)

__device__ inline void gload_lds16(const __bf16* g, __bf16* l) {
  __builtin_amdgcn_global_load_lds(
      (const __attribute__((address_space(1))) uint32_t*)g,
      (__attribute__((address_space(3))) uint32_t*)l, 16, 0, 0);
}

// ---------- prep: x f32->bf16 convert + 5 weight transposes, one launch -----
__global__ __launch_bounds__(256) void prep_kernel(
    const float* __restrict__ x, const float* __restrict__ wdkv,
    const float* __restrict__ wuk, const float* __restrict__ wuv,
    const float* __restrict__ wuq, const float* __restrict__ wo,
    __bf16* __restrict__ x_bf, __bf16* __restrict__ wt_dkv,
    __bf16* __restrict__ wt_uk, __bf16* __restrict__ wt_uv,
    __bf16* __restrict__ wt_uq, __bf16* __restrict__ wt_o) {
  int id = blockIdx.x;
  if (id < 2048) {
    int i = id * 256 + threadIdx.x;
    const float4* p = (const float4*)x;
    float4 a = p[2 * i], b = p[2 * i + 1];
    bf16x8 r = {(__bf16)a.x, (__bf16)a.y, (__bf16)a.z, (__bf16)a.w,
                (__bf16)b.x, (__bf16)b.y, (__bf16)b.z, (__bf16)b.w};
    *(bf16x8*)(x_bf + 8 * (size_t)i) = r;
    return;
  }
  int t = id - 2048;
  const float* in;
  __bf16* out;
  int R, C, lt;
  if (t < 64)       { in = wdkv; out = wt_dkv; R = 1024; C = 256;  lt = t; }
  else if (t < 128) { in = wuk;  out = wt_uk;  R = 256;  C = 1024; lt = t - 64; }
  else if (t < 192) { in = wuv;  out = wt_uv;  R = 256;  C = 1024; lt = t - 128; }
  else if (t < 448) { in = wuq;  out = wt_uq;  R = 1024; C = 1024; lt = t - 192; }
  else              { in = wo;   out = wt_o;   R = 1024; C = 1024; lt = t - 448; }
  __shared__ __bf16 tls[64][65];
  int tpr = C >> 6;
  int r0 = (lt / tpr) * 64, c0 = (lt % tpr) * 64;
  int tid = threadIdx.x;
#pragma unroll
  for (int i = 0; i < 16; i++) {
    int idx = tid + i * 256;
    int r = idx >> 6, c = idx & 63;
    tls[r][c] = (__bf16)in[(size_t)(r0 + r) * C + c0 + c];
  }
  __syncthreads();
#pragma unroll
  for (int i = 0; i < 16; i++) {
    int idx = tid + i * 256;
    int rr = idx & 63, cc = idx >> 6;
    out[(size_t)(c0 + cc) * R + r0 + rr] = tls[rr][cc];
  }
}

// ======== m97-pattern 128x128 GEMM core (round-8 single-buffer, 214us) ======
// ---------- gemm_a128: ckv = x@Wdkv' (bx<2), q = 0.125*x@Wuq' (bx>=2) -------
__global__ __launch_bounds__(256) void gemm_a128(const __bf16* __restrict__ A,
                                                 const __bf16* __restrict__ B1,
                                                 const __bf16* __restrict__ B2,
                                                 __bf16* __restrict__ C1,
                                                 __bf16* __restrict__ C2) {
  __shared__ __attribute__((aligned(16))) __bf16 Al[128 * 32];
  __shared__ __attribute__((aligned(16))) __bf16 Bl[128 * 32];
  int tid = threadIdx.x;
  int w = tid >> 6, lane = tid & 63;
  int quad = lane >> 4, l16 = lane & 15;
  int mw = w & 1, nw = w >> 1;
  int bx = blockIdx.x, m0 = blockIdx.y * 128;
  const __bf16* Bt;
  __bf16* C;
  int n0, N;
  float sc;
  if (bx < 2) { Bt = B1; C = C1; n0 = bx * 128; N = DLAT; sc = 1.0f; }
  else        { Bt = B2; C = C2; n0 = (bx - 2) * 128; N = DIMX; sc = 0.125f; }
  const int K = DIMX;
  int arow = w * 32 + (lane >> 2), acol = (lane & 3) << 3;

  floatx4 acc[4][4];
#pragma unroll
  for (int i = 0; i < 4; i++)
#pragma unroll
    for (int j = 0; j < 4; j++) acc[i][j] = (floatx4){0.f, 0.f, 0.f, 0.f};

  for (int k0 = 0; k0 < K; k0 += 32) {
#pragma unroll
    for (int j = 0; j < 2; j++) {
      gload_lds16(A + (size_t)(m0 + arow + j * 16) * K + k0 + acol,
                  &Al[(w * 32 + j * 16) * 32]);
      gload_lds16(Bt + (size_t)(n0 + arow + j * 16) * K + k0 + acol,
                  &Bl[(w * 32 + j * 16) * 32]);
    }
    __syncthreads();
    bf16x8 af[4], bfr[4];
#pragma unroll
    for (int mt = 0; mt < 4; mt++)
      af[mt] = *(const bf16x8*)&Al[(mw * 64 + mt * 16 + l16) * 32 + quad * 8];
#pragma unroll
    for (int nt = 0; nt < 4; nt++)
      bfr[nt] = *(const bf16x8*)&Bl[(nw * 64 + nt * 16 + l16) * 32 + quad * 8];
#pragma unroll
    for (int mt = 0; mt < 4; mt++)
#pragma unroll
      for (int nt = 0; nt < 4; nt++)
        acc[mt][nt] = MFMA(af[mt], bfr[nt], acc[mt][nt]);
    __syncthreads();
  }
#pragma unroll
  for (int mt = 0; mt < 4; mt++)
#pragma unroll
    for (int nt = 0; nt < 4; nt++)
#pragma unroll
      for (int r = 0; r < 4; r++) {
        int row = m0 + mw * 64 + mt * 16 + quad * 4 + r;
        int col = n0 + nw * 64 + nt * 16 + l16;
        C[(size_t)row * N + col] = (__bf16)(acc[mt][nt][r] * sc);
      }
}

// ---------- gemm_kv128: k = ckv@Wuk' (bx<8); vt = (ckv@Wuv')^T (bx>=8) ------
__global__ __launch_bounds__(256) void gemm_kv128(const __bf16* __restrict__ A,
                                                  const __bf16* __restrict__ Bk,
                                                  const __bf16* __restrict__ Bv,
                                                  __bf16* __restrict__ k,
                                                  __bf16* __restrict__ vt) {
  __shared__ __attribute__((aligned(16))) __bf16 Al[128 * 32];
  __shared__ __attribute__((aligned(16))) __bf16 Bl[128 * 32];
  __shared__ __attribute__((aligned(16))) __bf16 tw[4][64 * 72];
  int tid = threadIdx.x;
  int w = tid >> 6, lane = tid & 63;
  int quad = lane >> 4, l16 = lane & 15;
  int mw = w & 1, nw = w >> 1;
  int bx = blockIdx.x, m0 = blockIdx.y * 128;
  bool is_k = (bx < 8);
  const __bf16* Bt = is_k ? Bk : Bv;
  int n0 = (is_k ? bx : bx - 8) * 128;
  const int K = DLAT;
  int arow = w * 32 + (lane >> 2), acol = (lane & 3) << 3;

  floatx4 acc[4][4];
#pragma unroll
  for (int i = 0; i < 4; i++)
#pragma unroll
    for (int j = 0; j < 4; j++) acc[i][j] = (floatx4){0.f, 0.f, 0.f, 0.f};

  for (int k0 = 0; k0 < K; k0 += 32) {
#pragma unroll
    for (int j = 0; j < 2; j++) {
      gload_lds16(A + (size_t)(m0 + arow + j * 16) * K + k0 + acol,
                  &Al[(w * 32 + j * 16) * 32]);
      gload_lds16(Bt + (size_t)(n0 + arow + j * 16) * K + k0 + acol,
                  &Bl[(w * 32 + j * 16) * 32]);
    }
    __syncthreads();
    bf16x8 af[4], bfr[4];
#pragma unroll
    for (int mt = 0; mt < 4; mt++)
      af[mt] = *(const bf16x8*)&Al[(mw * 64 + mt * 16 + l16) * 32 + quad * 8];
#pragma unroll
    for (int nt = 0; nt < 4; nt++)
      bfr[nt] = *(const bf16x8*)&Bl[(nw * 64 + nt * 16 + l16) * 32 + quad * 8];
#pragma unroll
    for (int mt = 0; mt < 4; mt++)
#pragma unroll
      for (int nt = 0; nt < 4; nt++)
        acc[mt][nt] = MFMA(af[mt], bfr[nt], acc[mt][nt]);
    __syncthreads();
  }
  if (is_k) {
#pragma unroll
    for (int mt = 0; mt < 4; mt++)
#pragma unroll
      for (int nt = 0; nt < 4; nt++)
#pragma unroll
        for (int r = 0; r < 4; r++) {
          int row = m0 + mw * 64 + mt * 16 + quad * 4 + r;
          int col = n0 + nw * 64 + nt * 16 + l16;
          k[(size_t)row * DIMX + col] = (__bf16)acc[mt][nt][r];
        }
  } else {
#pragma unroll
    for (int mt = 0; mt < 4; mt++)
#pragma unroll
      for (int nt = 0; nt < 4; nt++)
#pragma unroll
        for (int r = 0; r < 4; r++)
          tw[w][(nt * 16 + l16) * 72 + mt * 16 + quad * 4 + r] =
              (__bf16)acc[mt][nt][r];
    int cbase = lane >> 3, chunk = lane & 7;
#pragma unroll
    for (int i = 0; i < 8; i++) {
      int c = cbase + i * 8;
      bf16x8 v8 = *(const bf16x8*)&tw[w][c * 72 + chunk * 8];
      *(bf16x8*)&vt[(size_t)(n0 + nw * 64 + c) * T_SEQ + m0 + mw * 64 +
                    chunk * 8] = v8;
    }
  }
}

// ---------- gemm_f128: out(f32) = ctx @ Wo' -------------------------------
__global__ __launch_bounds__(256) void gemm_f128(const __bf16* __restrict__ A,
                                                 const __bf16* __restrict__ Bt,
                                                 float* __restrict__ C) {
  __shared__ __attribute__((aligned(16))) __bf16 Al[128 * 32];
  __shared__ __attribute__((aligned(16))) __bf16 Bl[128 * 32];
  int tid = threadIdx.x;
  int w = tid >> 6, lane = tid & 63;
  int quad = lane >> 4, l16 = lane & 15;
  int mw = w & 1, nw = w >> 1;
  int n0 = blockIdx.x * 128, m0 = blockIdx.y * 128;
  const int K = DIMX, N = DIMX;
  int arow = w * 32 + (lane >> 2), acol = (lane & 3) << 3;

  floatx4 acc[4][4];
#pragma unroll
  for (int i = 0; i < 4; i++)
#pragma unroll
    for (int j = 0; j < 4; j++) acc[i][j] = (floatx4){0.f, 0.f, 0.f, 0.f};

  for (int k0 = 0; k0 < K; k0 += 32) {
#pragma unroll
    for (int j = 0; j < 2; j++) {
      gload_lds16(A + (size_t)(m0 + arow + j * 16) * K + k0 + acol,
                  &Al[(w * 32 + j * 16) * 32]);
      gload_lds16(Bt + (size_t)(n0 + arow + j * 16) * K + k0 + acol,
                  &Bl[(w * 32 + j * 16) * 32]);
    }
    __syncthreads();
    bf16x8 af[4], bfr[4];
#pragma unroll
    for (int mt = 0; mt < 4; mt++)
      af[mt] = *(const bf16x8*)&Al[(mw * 64 + mt * 16 + l16) * 32 + quad * 8];
#pragma unroll
    for (int nt = 0; nt < 4; nt++)
      bfr[nt] = *(const bf16x8*)&Bl[(nw * 64 + nt * 16 + l16) * 32 + quad * 8];
#pragma unroll
    for (int mt = 0; mt < 4; mt++)
#pragma unroll
      for (int nt = 0; nt < 4; nt++)
        acc[mt][nt] = MFMA(af[mt], bfr[nt], acc[mt][nt]);
    __syncthreads();
  }
#pragma unroll
  for (int mt = 0; mt < 4; mt++)
#pragma unroll
    for (int nt = 0; nt < 4; nt++)
#pragma unroll
      for (int r = 0; r < 4; r++) {
        int row = m0 + mw * 64 + mt * 16 + quad * 4 + r;
        int col = n0 + nw * 64 + nt * 16 + l16;
        C[(size_t)row * N + col] = acc[mt][nt][r];
      }
}

// ---------- flash attention v6: 256 thr, 32 q-rows per wave -----------------
// Each wave computes a 32x64 S strip: K/V B-frag reads amortized over 2 A-frags
// (36 -> 20 b128 reads per 32 rows). Waves 0-1 -> qa, 2-3 -> qb=63-qa; shared
// k-loop, fixed-max softmax, XOR-swizzled K/V, wave-private P slice (no extra
// barrier), dbuf staging + register prefetch, round-8 co-residency balance.
#define PST 72
__global__ __launch_bounds__(256, 2) void mla_attn6(const __bf16* __restrict__ Q,
                                                    const __bf16* __restrict__ Kg,
                                                    const __bf16* __restrict__ Vt,
                                                    __bf16* __restrict__ ctx) {
  __shared__ __attribute__((aligned(16))) __bf16 Kl[2][64 * 64];
  __shared__ __attribute__((aligned(16))) __bf16 Vl[2][64 * 64];
  __shared__ __attribute__((aligned(16))) __bf16 Pl[128 * PST];
  int tid = threadIdx.x;
  int w = tid >> 6, lane = tid & 63;
  int quad = lane >> 4, l16 = lane & 15;
  int tile = w >> 1, half = w & 1;
  int h = blockIdx.y;
  int qa = (h & 8) ? (31 - blockIdx.x) : blockIdx.x;
  int qb = 63 - qa;
  int myqt = tile ? qb : qa;
  int pbase = tile * 64 + half * 32;  // this wave's Pl row base (32 rows)
  int srow = tid >> 3, pos = tid & 7;
  int gco = pos << 3;
  int sw = (pos ^ (srow & 7)) << 3;

  // stage Q tiles into Pl: rows 0-63 = qa, 64-127 = qb (4 passes of 32 rows)
#pragma unroll
  for (int i = 0; i < 4; i++) {
    int prow = srow + i * 32;
    int grow = (i < 2 ? qa : qb) * 64 + srow + (i & 1) * 32;
    *(bf16x8*)&Pl[prow * PST + gco] =
        *(const bf16x8*)&Q[(size_t)grow * DIMX + h * HD + gco];
  }
  // stage K/V tile 0 (swizzled, 2 passes of 32 rows)
#pragma unroll
  for (int i = 0; i < 2; i++) {
    int r = srow + i * 32;
    int a = r * 64 + sw;  // (r&7)==(srow&7) so sw is valid for both passes
    *(bf16x8*)&Kl[0][a] = *(const bf16x8*)&Kg[(size_t)r * DIMX + h * HD + gco];
    *(bf16x8*)&Vl[0][a] = *(const bf16x8*)&Vt[(size_t)(h * HD + r) * T_SEQ + gco];
  }
  __syncthreads();
  // Q A-frags: 2 row-halves x 2 k-halves, held in registers
  bf16x8 qf[2][2];
#pragma unroll
  for (int rt = 0; rt < 2; rt++)
#pragma unroll
    for (int kh = 0; kh < 2; kh++)
      qf[rt][kh] = *(const bf16x8*)&Pl[(pbase + rt * 16 + l16) * PST + kh * 32 +
                                       quad * 8];

  floatx4 o[2][4];
  float l_i[2][4];
#pragma unroll
  for (int rt = 0; rt < 2; rt++)
#pragma unroll
    for (int i = 0; i < 4; i++) {
      o[rt][i] = (floatx4){0.f, 0.f, 0.f, 0.f};
      l_i[rt][i] = 0.f;
    }

  for (int kt = 0; kt <= qb; kt++) {
    int cur = kt & 1, nxt = cur ^ 1;
    bool pre = (kt < qb);
    bf16x8 kpre[2], vpre[2];
    if (pre) {
      int k0n = (kt + 1) * 64;
#pragma unroll
      for (int i = 0; i < 2; i++) {
        int r = srow + i * 32;
        kpre[i] = *(const bf16x8*)&Kg[(size_t)(k0n + r) * DIMX + h * HD + gco];
        vpre[i] = *(const bf16x8*)&Vt[(size_t)(h * HD + r) * T_SEQ + k0n + gco];
      }
    }
    if (tile || kt <= qa) {
      const __bf16* Kc = Kl[cur];
      const __bf16* Vc = Vl[cur];
      // QK^T: 8 K-frag reads shared by both row-halves -> 16 MFMA
      floatx4 s[2][4];
#pragma unroll
      for (int ct = 0; ct < 4; ct++) {
        int rb = (ct * 16 + l16) * 64;
        bf16x8 kf0 = *(const bf16x8*)&Kc[rb + ((quad ^ (l16 & 7)) << 3)];
        bf16x8 kf1 = *(const bf16x8*)&Kc[rb + (((4 + quad) ^ (l16 & 7)) << 3)];
#pragma unroll
        for (int rt = 0; rt < 2; rt++) {
          floatx4 z = (floatx4){0.f, 0.f, 0.f, 0.f};
          z = MFMA(qf[rt][0], kf0, z);
          z = MFMA(qf[rt][1], kf1, z);
          s[rt][ct] = z;
        }
      }
      bool diag = (kt == myqt);
      // fixed-max softmax + P write to wave-private Pl slice
#pragma unroll
      for (int rt = 0; rt < 2; rt++)
#pragma unroll
        for (int ct = 0; ct < 4; ct++)
#pragma unroll
          for (int r = 0; r < 4; r++) {
            float p = __expf(s[rt][ct][r]);
            if (diag &&
                (ct * 16 + l16 > half * 32 + rt * 16 + quad * 4 + r))
              p = 0.f;
            l_i[rt][r] += p;
            Pl[(pbase + rt * 16 + quad * 4 + r) * PST + ct * 16 + l16] =
                (__bf16)p;
          }
      // P A-frags (in-wave lgkm ordering; wave-private rows)
      bf16x8 pf[2][2];
#pragma unroll
      for (int rt = 0; rt < 2; rt++)
#pragma unroll
        for (int kh = 0; kh < 2; kh++)
          pf[rt][kh] = *(const bf16x8*)&Pl[(pbase + rt * 16 + l16) * PST +
                                           kh * 32 + quad * 8];
      // PV: 8 V-frag reads shared by both row-halves -> 16 MFMA
#pragma unroll
      for (int dt = 0; dt < 4; dt++) {
        int rb = (dt * 16 + l16) * 64;
        bf16x8 vf0 = *(const bf16x8*)&Vc[rb + ((quad ^ (l16 & 7)) << 3)];
        bf16x8 vf1 = *(const bf16x8*)&Vc[rb + (((4 + quad) ^ (l16 & 7)) << 3)];
#pragma unroll
        for (int rt = 0; rt < 2; rt++) {
          o[rt][dt] = MFMA(pf[rt][0], vf0, o[rt][dt]);
          o[rt][dt] = MFMA(pf[rt][1], vf1, o[rt][dt]);
        }
      }
    }
    if (pre) {
#pragma unroll
      for (int i = 0; i < 2; i++) {
        int a = (srow + i * 32) * 64 + sw;
        *(bf16x8*)&Kl[nxt][a] = kpre[i];
        *(bf16x8*)&Vl[nxt][a] = vpre[i];
      }
    }
    __syncthreads();  // the ONLY barrier in the k-loop
  }

#pragma unroll
  for (int off = 1; off < 16; off <<= 1)
#pragma unroll
    for (int rt = 0; rt < 2; rt++)
#pragma unroll
      for (int r = 0; r < 4; r++)
        l_i[rt][r] += __shfl_xor(l_i[rt][r], off, 64);

#pragma unroll
  for (int rt = 0; rt < 2; rt++)
#pragma unroll
    for (int dt = 0; dt < 4; dt++)
#pragma unroll
      for (int r = 0; r < 4; r++) {
        float val = o[rt][dt][r] / l_i[rt][r];
        int row = myqt * 64 + half * 32 + rt * 16 + quad * 4 + r;
        int col = h * HD + dt * 16 + l16;
        ctx[(size_t)row * DIMX + col] = (__bf16)val;
      }
}

extern "C" void kernel_launch(void* const* d_in, const int* in_sizes, int n_in,
                              void* d_out, int out_size, void* d_ws,
                              size_t ws_size, hipStream_t stream) {
  const float* x = (const float*)d_in[0];
  const float* wdkv = (const float*)d_in[1];
  const float* wuk = (const float*)d_in[2];
  const float* wuv = (const float*)d_in[3];
  const float* wuq = (const float*)d_in[4];
  const float* wo = (const float*)d_in[5];
  float* out = (float*)d_out;

  __bf16* ws = (__bf16*)d_ws;
  __bf16* x_bf = ws;                               // T*D
  __bf16* q = x_bf + (size_t)T_SEQ * DIMX;         // T*D (pre-scaled by 1/8)
  __bf16* k = q + (size_t)T_SEQ * DIMX;            // T*D
  __bf16* vt = k + (size_t)T_SEQ * DIMX;           // D*T
  __bf16* ctx = vt + (size_t)T_SEQ * DIMX;         // T*D
  __bf16* ckv = ctx + (size_t)T_SEQ * DIMX;        // T*DLAT
  __bf16* wt_dkv = ckv + (size_t)T_SEQ * DLAT;     // DLAT x DIM
  __bf16* wt_uk = wt_dkv + (size_t)DLAT * DIMX;    // DIM x DLAT
  __bf16* wt_uv = wt_uk + (size_t)DIMX * DLAT;     // DIM x DLAT
  __bf16* wt_uq = wt_uv + (size_t)DIMX * DLAT;     // DIM x DIM
  __bf16* wt_o = wt_uq + (size_t)DIMX * DIMX;      // DIM x DIM

  dim3 blk(256);
  prep_kernel<<<dim3(2752), blk, 0, stream>>>(x, wdkv, wuk, wuv, wuq, wo, x_bf,
                                              wt_dkv, wt_uk, wt_uv, wt_uq, wt_o);
  gemm_a128<<<dim3(10, T_SEQ / 128), blk, 0, stream>>>(x_bf, wt_dkv, wt_uq,
                                                       ckv, q);
  gemm_kv128<<<dim3(16, T_SEQ / 128), blk, 0, stream>>>(ckv, wt_uk, wt_uv, k,
                                                        vt);
  mla_attn6<<<dim3(32, NH), blk, 0, stream>>>(q, k, vt, ctx);
  gemm_f128<<<dim3(DIMX / 128, T_SEQ / 128), blk, 0, stream>>>(ctx, wt_o, out);
}

// Round 11
// 225.979 us; speedup vs baseline: 1.0123x; 1.0123x over previous
//
#include <hip/hip_runtime.h>
#include <hip/hip_bf16.h>
#include <stdint.h>

#define T_SEQ 4096
#define DIMX 1024
#define NH 16
#define HD 64
#define DLAT 256

typedef __bf16 bf16x8 __attribute__((ext_vector_type(8)));
typedef float floatx4 __attribute__((ext_vector_type(4)));

#define MFMA(a, b, c) __builtin_amdgcn_mfma_f32_16x16x32_bf16(a, b, c, 0, 0, 0)

__device__ inline void gload_lds16(const __bf16* g, __bf16* l) {
  __builtin_amdgcn_global_load_lds(
      (const __attribute__((address_space(1))) uint32_t*)g,
      (__attribute__((address_space(3))) uint32_t*)l, 16, 0, 0);
}

// ---------- prep: 5 weight transposes only (x-convert fused into gemm_a) ----
__global__ __launch_bounds__(256) void prep_kernel(
    const float* __restrict__ wdkv, const float* __restrict__ wuk,
    const float* __restrict__ wuv, const float* __restrict__ wuq,
    const float* __restrict__ wo, __bf16* __restrict__ wt_dkv,
    __bf16* __restrict__ wt_uk, __bf16* __restrict__ wt_uv,
    __bf16* __restrict__ wt_uq, __bf16* __restrict__ wt_o) {
  int t = blockIdx.x;
  const float* in;
  __bf16* out;
  int R, C, lt;
  if (t < 64)       { in = wdkv; out = wt_dkv; R = 1024; C = 256;  lt = t; }
  else if (t < 128) { in = wuk;  out = wt_uk;  R = 256;  C = 1024; lt = t - 64; }
  else if (t < 192) { in = wuv;  out = wt_uv;  R = 256;  C = 1024; lt = t - 128; }
  else if (t < 448) { in = wuq;  out = wt_uq;  R = 1024; C = 1024; lt = t - 192; }
  else              { in = wo;   out = wt_o;   R = 1024; C = 1024; lt = t - 448; }
  __shared__ __bf16 tls[64][65];
  int tpr = C >> 6;
  int r0 = (lt / tpr) * 64, c0 = (lt % tpr) * 64;
  int tid = threadIdx.x;
#pragma unroll
  for (int i = 0; i < 16; i++) {
    int idx = tid + i * 256;
    int r = idx >> 6, c = idx & 63;
    tls[r][c] = (__bf16)in[(size_t)(r0 + r) * C + c0 + c];
  }
  __syncthreads();
#pragma unroll
  for (int i = 0; i < 16; i++) {
    int idx = tid + i * 256;
    int rr = idx & 63, cc = idx >> 6;
    out[(size_t)(c0 + cc) * R + r0 + rr] = tls[rr][cc];
  }
}

// ---------- gemm_af: A = x (f32, converted in-staging); two B targets -------
// ckv = x@Wdkv' (bx<2), q = 0.125*x@Wuq' (bx>=2). B staged via global_load_lds.
__global__ __launch_bounds__(256) void gemm_af(const float* __restrict__ X,
                                               const __bf16* __restrict__ B1,
                                               const __bf16* __restrict__ B2,
                                               __bf16* __restrict__ C1,
                                               __bf16* __restrict__ C2) {
  __shared__ __attribute__((aligned(16))) __bf16 Al[128 * 32];
  __shared__ __attribute__((aligned(16))) __bf16 Bl[128 * 32];
  int tid = threadIdx.x;
  int w = tid >> 6, lane = tid & 63;
  int quad = lane >> 4, l16 = lane & 15;
  int mw = w & 1, nw = w >> 1;
  int bx = blockIdx.x, m0 = blockIdx.y * 128;
  const __bf16* Bt;
  __bf16* C;
  int n0, N;
  float sc;
  if (bx < 2) { Bt = B1; C = C1; n0 = bx * 128; N = DLAT; sc = 1.0f; }
  else        { Bt = B2; C = C2; n0 = (bx - 2) * 128; N = DIMX; sc = 0.125f; }
  const int K = DIMX;
  int arow = w * 32 + (lane >> 2), acol = (lane & 3) << 3;

  floatx4 acc[4][4];
#pragma unroll
  for (int i = 0; i < 4; i++)
#pragma unroll
    for (int j = 0; j < 4; j++) acc[i][j] = (floatx4){0.f, 0.f, 0.f, 0.f};

  for (int k0 = 0; k0 < K; k0 += 32) {
    // B: async staging (16B/lane x2)
#pragma unroll
    for (int j = 0; j < 2; j++)
      gload_lds16(Bt + (size_t)(n0 + arow + j * 16) * K + k0 + acol,
                  &Bl[(w * 32 + j * 16) * 32]);
    // A: f32 load -> cvt -> ds_write_b128 (2-way bank alias = free)
#pragma unroll
    for (int j = 0; j < 2; j++) {
      const float* src = X + (size_t)(m0 + arow + j * 16) * K + k0 + acol;
      float4 a = *(const float4*)src;
      float4 b = *(const float4*)(src + 4);
      bf16x8 v = {(__bf16)a.x, (__bf16)a.y, (__bf16)a.z, (__bf16)a.w,
                  (__bf16)b.x, (__bf16)b.y, (__bf16)b.z, (__bf16)b.w};
      *(bf16x8*)&Al[((arow + j * 16)) * 32 + acol] = v;
    }
    __syncthreads();
    bf16x8 af[4], bfr[4];
#pragma unroll
    for (int mt = 0; mt < 4; mt++)
      af[mt] = *(const bf16x8*)&Al[(mw * 64 + mt * 16 + l16) * 32 + quad * 8];
#pragma unroll
    for (int nt = 0; nt < 4; nt++)
      bfr[nt] = *(const bf16x8*)&Bl[(nw * 64 + nt * 16 + l16) * 32 + quad * 8];
#pragma unroll
    for (int mt = 0; mt < 4; mt++)
#pragma unroll
      for (int nt = 0; nt < 4; nt++)
        acc[mt][nt] = MFMA(af[mt], bfr[nt], acc[mt][nt]);
    __syncthreads();
  }
#pragma unroll
  for (int mt = 0; mt < 4; mt++)
#pragma unroll
    for (int nt = 0; nt < 4; nt++)
#pragma unroll
      for (int r = 0; r < 4; r++) {
        int row = m0 + mw * 64 + mt * 16 + quad * 4 + r;
        int col = n0 + nw * 64 + nt * 16 + l16;
        C[(size_t)row * N + col] = (__bf16)(acc[mt][nt][r] * sc);
      }
}

// ---------- gemm_kv128: k = ckv@Wuk' (bx<8); vt = (ckv@Wuv')^T (bx>=8) ------
__global__ __launch_bounds__(256) void gemm_kv128(const __bf16* __restrict__ A,
                                                  const __bf16* __restrict__ Bk,
                                                  const __bf16* __restrict__ Bv,
                                                  __bf16* __restrict__ k,
                                                  __bf16* __restrict__ vt) {
  __shared__ __attribute__((aligned(16))) __bf16 Al[128 * 32];
  __shared__ __attribute__((aligned(16))) __bf16 Bl[128 * 32];
  __shared__ __attribute__((aligned(16))) __bf16 tw[4][64 * 72];
  int tid = threadIdx.x;
  int w = tid >> 6, lane = tid & 63;
  int quad = lane >> 4, l16 = lane & 15;
  int mw = w & 1, nw = w >> 1;
  int bx = blockIdx.x, m0 = blockIdx.y * 128;
  bool is_k = (bx < 8);
  const __bf16* Bt = is_k ? Bk : Bv;
  int n0 = (is_k ? bx : bx - 8) * 128;
  const int K = DLAT;
  int arow = w * 32 + (lane >> 2), acol = (lane & 3) << 3;

  floatx4 acc[4][4];
#pragma unroll
  for (int i = 0; i < 4; i++)
#pragma unroll
    for (int j = 0; j < 4; j++) acc[i][j] = (floatx4){0.f, 0.f, 0.f, 0.f};

  for (int k0 = 0; k0 < K; k0 += 32) {
#pragma unroll
    for (int j = 0; j < 2; j++) {
      gload_lds16(A + (size_t)(m0 + arow + j * 16) * K + k0 + acol,
                  &Al[(w * 32 + j * 16) * 32]);
      gload_lds16(Bt + (size_t)(n0 + arow + j * 16) * K + k0 + acol,
                  &Bl[(w * 32 + j * 16) * 32]);
    }
    __syncthreads();
    bf16x8 af[4], bfr[4];
#pragma unroll
    for (int mt = 0; mt < 4; mt++)
      af[mt] = *(const bf16x8*)&Al[(mw * 64 + mt * 16 + l16) * 32 + quad * 8];
#pragma unroll
    for (int nt = 0; nt < 4; nt++)
      bfr[nt] = *(const bf16x8*)&Bl[(nw * 64 + nt * 16 + l16) * 32 + quad * 8];
#pragma unroll
    for (int mt = 0; mt < 4; mt++)
#pragma unroll
      for (int nt = 0; nt < 4; nt++)
        acc[mt][nt] = MFMA(af[mt], bfr[nt], acc[mt][nt]);
    __syncthreads();
  }
  if (is_k) {
#pragma unroll
    for (int mt = 0; mt < 4; mt++)
#pragma unroll
      for (int nt = 0; nt < 4; nt++)
#pragma unroll
        for (int r = 0; r < 4; r++) {
          int row = m0 + mw * 64 + mt * 16 + quad * 4 + r;
          int col = n0 + nw * 64 + nt * 16 + l16;
          k[(size_t)row * DIMX + col] = (__bf16)acc[mt][nt][r];
        }
  } else {
#pragma unroll
    for (int mt = 0; mt < 4; mt++)
#pragma unroll
      for (int nt = 0; nt < 4; nt++)
#pragma unroll
        for (int r = 0; r < 4; r++)
          tw[w][(nt * 16 + l16) * 72 + mt * 16 + quad * 4 + r] =
              (__bf16)acc[mt][nt][r];
    int cbase = lane >> 3, chunk = lane & 7;
#pragma unroll
    for (int i = 0; i < 8; i++) {
      int c = cbase + i * 8;
      bf16x8 v8 = *(const bf16x8*)&tw[w][c * 72 + chunk * 8];
      *(bf16x8*)&vt[(size_t)(n0 + nw * 64 + c) * T_SEQ + m0 + mw * 64 +
                    chunk * 8] = v8;
    }
  }
}

// ---------- gemm_f128: out(f32) = ctx @ Wo' -------------------------------
__global__ __launch_bounds__(256) void gemm_f128(const __bf16* __restrict__ A,
                                                 const __bf16* __restrict__ Bt,
                                                 float* __restrict__ C) {
  __shared__ __attribute__((aligned(16))) __bf16 Al[128 * 32];
  __shared__ __attribute__((aligned(16))) __bf16 Bl[128 * 32];
  int tid = threadIdx.x;
  int w = tid >> 6, lane = tid & 63;
  int quad = lane >> 4, l16 = lane & 15;
  int mw = w & 1, nw = w >> 1;
  int n0 = blockIdx.x * 128, m0 = blockIdx.y * 128;
  const int K = DIMX, N = DIMX;
  int arow = w * 32 + (lane >> 2), acol = (lane & 3) << 3;

  floatx4 acc[4][4];
#pragma unroll
  for (int i = 0; i < 4; i++)
#pragma unroll
    for (int j = 0; j < 4; j++) acc[i][j] = (floatx4){0.f, 0.f, 0.f, 0.f};

  for (int k0 = 0; k0 < K; k0 += 32) {
#pragma unroll
    for (int j = 0; j < 2; j++) {
      gload_lds16(A + (size_t)(m0 + arow + j * 16) * K + k0 + acol,
                  &Al[(w * 32 + j * 16) * 32]);
      gload_lds16(Bt + (size_t)(n0 + arow + j * 16) * K + k0 + acol,
                  &Bl[(w * 32 + j * 16) * 32]);
    }
    __syncthreads();
    bf16x8 af[4], bfr[4];
#pragma unroll
    for (int mt = 0; mt < 4; mt++)
      af[mt] = *(const bf16x8*)&Al[(mw * 64 + mt * 16 + l16) * 32 + quad * 8];
#pragma unroll
    for (int nt = 0; nt < 4; nt++)
      bfr[nt] = *(const bf16x8*)&Bl[(nw * 64 + nt * 16 + l16) * 32 + quad * 8];
#pragma unroll
    for (int mt = 0; mt < 4; mt++)
#pragma unroll
      for (int nt = 0; nt < 4; nt++)
        acc[mt][nt] = MFMA(af[mt], bfr[nt], acc[mt][nt]);
    __syncthreads();
  }
#pragma unroll
  for (int mt = 0; mt < 4; mt++)
#pragma unroll
    for (int nt = 0; nt < 4; nt++)
#pragma unroll
      for (int r = 0; r < 4; r++) {
        int row = m0 + mw * 64 + mt * 16 + quad * 4 + r;
        int col = n0 + nw * 64 + nt * 16 + l16;
        C[(size_t)row * N + col] = acc[mt][nt][r];
      }
}

// ---------- flash attention (round-8 attn5, 84us validated) -----------------
#define PST 72
__global__ __launch_bounds__(512, 4) void mla_attn5(const __bf16* __restrict__ Q,
                                                    const __bf16* __restrict__ Kg,
                                                    const __bf16* __restrict__ Vt,
                                                    __bf16* __restrict__ ctx) {
  __shared__ __attribute__((aligned(16))) __bf16 Kl[2][64 * 64];
  __shared__ __attribute__((aligned(16))) __bf16 Vl[2][64 * 64];
  __shared__ __attribute__((aligned(16))) __bf16 Pl[128 * PST];
  int tid = threadIdx.x;
  int wave = tid >> 6, lane = tid & 63;
  int quad = lane >> 4, l16 = lane & 15;
  int wq = wave & 3;
  bool isA = (wave < 4);
  int h = blockIdx.y;
  int qa = (h & 8) ? (31 - blockIdx.x) : blockIdx.x;
  int qb = 63 - qa;
  int myqt = isA ? qa : qb;
  int myq0 = myqt * 64;
  int srow = tid >> 3, pos = tid & 7;
  int gco = pos << 3;
  int sw = ((pos ^ (srow & 7)) << 3);
  int swr = srow * 64 + sw;

  *(bf16x8*)&Pl[srow * PST + gco] =
      *(const bf16x8*)&Q[(size_t)(qa * 64 + srow) * DIMX + h * HD + gco];
  *(bf16x8*)&Pl[(64 + srow) * PST + gco] =
      *(const bf16x8*)&Q[(size_t)(qb * 64 + srow) * DIMX + h * HD + gco];
  *(bf16x8*)&Kl[0][swr] =
      *(const bf16x8*)&Kg[(size_t)srow * DIMX + h * HD + gco];
  *(bf16x8*)&Vl[0][swr] =
      *(const bf16x8*)&Vt[(size_t)(h * HD + srow) * T_SEQ + gco];
  __syncthreads();
  int fr = (wave * 16 + l16) * PST;
  bf16x8 qf0 = *(const bf16x8*)&Pl[fr + quad * 8];
  bf16x8 qf1 = *(const bf16x8*)&Pl[fr + 32 + quad * 8];

  int c0s = ((quad ^ (l16 & 7)) << 3);
  int c1s = (((4 + quad) ^ (l16 & 7)) << 3);

  floatx4 o[4];
  float l_i[4];
#pragma unroll
  for (int i = 0; i < 4; i++) {
    o[i] = (floatx4){0.f, 0.f, 0.f, 0.f};
    l_i[i] = 0.f;
  }

  for (int kt = 0; kt <= qb; kt++) {
    int cur = kt & 1, nxt = cur ^ 1;
    bool pre = (kt < qb);
    bf16x8 kpre, vpre;
    if (pre) {
      int k0n = (kt + 1) * 64;
      kpre = *(const bf16x8*)&Kg[(size_t)(k0n + srow) * DIMX + h * HD + gco];
      vpre = *(const bf16x8*)&Vt[(size_t)(h * HD + srow) * T_SEQ + k0n + gco];
    }
    if (!isA || kt <= qa) {
      const __bf16* Kc = Kl[cur];
      const __bf16* Vc = Vl[cur];
      floatx4 s[4];
#pragma unroll
      for (int ct = 0; ct < 4; ct++) {
        int rb = (ct * 16 + l16) * 64;
        bf16x8 kf0 = *(const bf16x8*)&Kc[rb + c0s];
        bf16x8 kf1 = *(const bf16x8*)&Kc[rb + c1s];
        floatx4 z = (floatx4){0.f, 0.f, 0.f, 0.f};
        z = MFMA(qf0, kf0, z);
        z = MFMA(qf1, kf1, z);
        s[ct] = z;
      }
      bool diag = (kt == myqt);
#pragma unroll
      for (int ct = 0; ct < 4; ct++)
#pragma unroll
        for (int r = 0; r < 4; r++) {
          float p = __expf(s[ct][r]);
          if (diag && (ct * 16 + l16 > wq * 16 + quad * 4 + r)) p = 0.f;
          l_i[r] += p;
          Pl[(wave * 16 + quad * 4 + r) * PST + ct * 16 + l16] = (__bf16)p;
        }
      bf16x8 pf0 = *(const bf16x8*)&Pl[fr + quad * 8];
      bf16x8 pf1 = *(const bf16x8*)&Pl[fr + 32 + quad * 8];
#pragma unroll
      for (int dt = 0; dt < 4; dt++) {
        int rb = (dt * 16 + l16) * 64;
        bf16x8 vf0 = *(const bf16x8*)&Vc[rb + c0s];
        bf16x8 vf1 = *(const bf16x8*)&Vc[rb + c1s];
        o[dt] = MFMA(pf0, vf0, o[dt]);
        o[dt] = MFMA(pf1, vf1, o[dt]);
      }
    }
    if (pre) {
      *(bf16x8*)&Kl[nxt][swr] = kpre;
      *(bf16x8*)&Vl[nxt][swr] = vpre;
    }
    __syncthreads();
  }

#pragma unroll
  for (int off = 1; off < 16; off <<= 1)
#pragma unroll
    for (int r = 0; r < 4; r++) l_i[r] += __shfl_xor(l_i[r], off, 64);

#pragma unroll
  for (int dt = 0; dt < 4; dt++)
#pragma unroll
    for (int r = 0; r < 4; r++) {
      float val = o[dt][r] / l_i[r];
      int row = myq0 + wq * 16 + quad * 4 + r;
      int col = h * HD + dt * 16 + l16;
      ctx[(size_t)row * DIMX + col] = (__bf16)val;
    }
}

extern "C" void kernel_launch(void* const* d_in, const int* in_sizes, int n_in,
                              void* d_out, int out_size, void* d_ws,
                              size_t ws_size, hipStream_t stream) {
  const float* x = (const float*)d_in[0];
  const float* wdkv = (const float*)d_in[1];
  const float* wuk = (const float*)d_in[2];
  const float* wuv = (const float*)d_in[3];
  const float* wuq = (const float*)d_in[4];
  const float* wo = (const float*)d_in[5];
  float* out = (float*)d_out;

  __bf16* ws = (__bf16*)d_ws;
  __bf16* q = ws;                                  // T*D (pre-scaled by 1/8)
  __bf16* k = q + (size_t)T_SEQ * DIMX;            // T*D
  __bf16* vt = k + (size_t)T_SEQ * DIMX;           // D*T
  __bf16* ctx = vt + (size_t)T_SEQ * DIMX;         // T*D
  __bf16* ckv = ctx + (size_t)T_SEQ * DIMX;        // T*DLAT
  __bf16* wt_dkv = ckv + (size_t)T_SEQ * DLAT;     // DLAT x DIM
  __bf16* wt_uk = wt_dkv + (size_t)DLAT * DIMX;    // DIM x DLAT
  __bf16* wt_uv = wt_uk + (size_t)DIMX * DLAT;     // DIM x DLAT
  __bf16* wt_uq = wt_uv + (size_t)DIMX * DLAT;     // DIM x DIM
  __bf16* wt_o = wt_uq + (size_t)DIMX * DIMX;      // DIM x DIM

  dim3 blk(256);
  prep_kernel<<<dim3(704), blk, 0, stream>>>(wdkv, wuk, wuv, wuq, wo, wt_dkv,
                                             wt_uk, wt_uv, wt_uq, wt_o);
  gemm_af<<<dim3(10, T_SEQ / 128), blk, 0, stream>>>(x, wt_dkv, wt_uq, ckv, q);
  gemm_kv128<<<dim3(16, T_SEQ / 128), blk, 0, stream>>>(ckv, wt_uk, wt_uv, k,
                                                        vt);
  mla_attn5<<<dim3(32, NH), dim3(512), 0, stream>>>(q, k, vt, ctx);
  gemm_f128<<<dim3(DIMX / 128, T_SEQ / 128), blk, 0, stream>>>(ctx, wt_o, out);
}

// Round 12
// 213.274 us; speedup vs baseline: 1.0726x; 1.0596x over previous
//
#include <hip/hip_runtime.h>
#include <hip/hip_bf16.h>
#include <stdint.h>

#define T_SEQ 4096
#define DIMX 1024
#define NH 16
#define HD 64
#define DLAT 256

typedef __bf16 bf16x8 __attribute__((ext_vector_type(8)));
typedef float floatx4 __attribute__((ext_vector_type(4)));

#define MFMA(a, b, c) __builtin_amdgcn_mfma_f32_16x16x32_bf16(a, b, c, 0, 0, 0)

__device__ inline void gload_lds16(const __bf16* g, __bf16* l) {
  __builtin_amdgcn_global_load_lds(
      (const __attribute__((address_space(1))) uint32_t*)g,
      (__attribute__((address_space(3))) uint32_t*)l, 16, 0, 0);
}

// ---------- prep: x f32->bf16 convert + 5 weight transposes (round-8) -------
__global__ __launch_bounds__(256) void prep_kernel(
    const float* __restrict__ x, const float* __restrict__ wdkv,
    const float* __restrict__ wuk, const float* __restrict__ wuv,
    const float* __restrict__ wuq, const float* __restrict__ wo,
    __bf16* __restrict__ x_bf, __bf16* __restrict__ wt_dkv,
    __bf16* __restrict__ wt_uk, __bf16* __restrict__ wt_uv,
    __bf16* __restrict__ wt_uq, __bf16* __restrict__ wt_o) {
  int id = blockIdx.x;
  if (id < 2048) {
    int i = id * 256 + threadIdx.x;
    const float4* p = (const float4*)x;
    float4 a = p[2 * i], b = p[2 * i + 1];
    bf16x8 r = {(__bf16)a.x, (__bf16)a.y, (__bf16)a.z, (__bf16)a.w,
                (__bf16)b.x, (__bf16)b.y, (__bf16)b.z, (__bf16)b.w};
    *(bf16x8*)(x_bf + 8 * (size_t)i) = r;
    return;
  }
  int t = id - 2048;
  const float* in;
  __bf16* out;
  int R, C, lt;
  if (t < 64)       { in = wdkv; out = wt_dkv; R = 1024; C = 256;  lt = t; }
  else if (t < 128) { in = wuk;  out = wt_uk;  R = 256;  C = 1024; lt = t - 64; }
  else if (t < 192) { in = wuv;  out = wt_uv;  R = 256;  C = 1024; lt = t - 128; }
  else if (t < 448) { in = wuq;  out = wt_uq;  R = 1024; C = 1024; lt = t - 192; }
  else              { in = wo;   out = wt_o;   R = 1024; C = 1024; lt = t - 448; }
  __shared__ __bf16 tls[64][65];
  int tpr = C >> 6;
  int r0 = (lt / tpr) * 64, c0 = (lt % tpr) * 64;
  int tid = threadIdx.x;
#pragma unroll
  for (int i = 0; i < 16; i++) {
    int idx = tid + i * 256;
    int r = idx >> 6, c = idx & 63;
    tls[r][c] = (__bf16)in[(size_t)(r0 + r) * C + c0 + c];
  }
  __syncthreads();
#pragma unroll
  for (int i = 0; i < 16; i++) {
    int idx = tid + i * 256;
    int rr = idx & 63, cc = idx >> 6;
    out[(size_t)(c0 + cc) * R + r0 + rr] = tls[rr][cc];
  }
}

// ======== 128x128 GEMM, BK=64 via two independent BK=32 buffers =============
// Layout/ds_read pattern byte-identical to validated round-8; barriers halved.
#define BUFE 4096  // 128*32

// ---------- gemm_a128: ckv = x@Wdkv' (bx<2), q = 0.125*x@Wuq' (bx>=2) -------
__global__ __launch_bounds__(256) void gemm_a128(const __bf16* __restrict__ A,
                                                 const __bf16* __restrict__ B1,
                                                 const __bf16* __restrict__ B2,
                                                 __bf16* __restrict__ C1,
                                                 __bf16* __restrict__ C2) {
  __shared__ __attribute__((aligned(16))) __bf16 Al[2][BUFE];
  __shared__ __attribute__((aligned(16))) __bf16 Bl[2][BUFE];
  int tid = threadIdx.x;
  int w = tid >> 6, lane = tid & 63;
  int quad = lane >> 4, l16 = lane & 15;
  int mw = w & 1, nw = w >> 1;
  int bx = blockIdx.x, m0 = blockIdx.y * 128;
  const __bf16* Bt;
  __bf16* C;
  int n0, N;
  float sc;
  if (bx < 2) { Bt = B1; C = C1; n0 = bx * 128; N = DLAT; sc = 1.0f; }
  else        { Bt = B2; C = C2; n0 = (bx - 2) * 128; N = DIMX; sc = 0.125f; }
  const int K = DIMX;
  int arow = w * 32 + (lane >> 2), acol = (lane & 3) << 3;

  floatx4 acc[4][4];
#pragma unroll
  for (int i = 0; i < 4; i++)
#pragma unroll
    for (int j = 0; j < 4; j++) acc[i][j] = (floatx4){0.f, 0.f, 0.f, 0.f};

  for (int k0 = 0; k0 < K; k0 += 64) {
#pragma unroll
    for (int kh = 0; kh < 2; kh++)
#pragma unroll
      for (int j = 0; j < 2; j++) {
        gload_lds16(A + (size_t)(m0 + arow + j * 16) * K + k0 + kh * 32 + acol,
                    &Al[kh][(w * 32 + j * 16) * 32]);
        gload_lds16(Bt + (size_t)(n0 + arow + j * 16) * K + k0 + kh * 32 + acol,
                    &Bl[kh][(w * 32 + j * 16) * 32]);
      }
    __syncthreads();
#pragma unroll
    for (int kh = 0; kh < 2; kh++) {
      bf16x8 af[4], bfr[4];
#pragma unroll
      for (int mt = 0; mt < 4; mt++)
        af[mt] =
            *(const bf16x8*)&Al[kh][(mw * 64 + mt * 16 + l16) * 32 + quad * 8];
#pragma unroll
      for (int nt = 0; nt < 4; nt++)
        bfr[nt] =
            *(const bf16x8*)&Bl[kh][(nw * 64 + nt * 16 + l16) * 32 + quad * 8];
#pragma unroll
      for (int mt = 0; mt < 4; mt++)
#pragma unroll
        for (int nt = 0; nt < 4; nt++)
          acc[mt][nt] = MFMA(af[mt], bfr[nt], acc[mt][nt]);
    }
    __syncthreads();
  }
#pragma unroll
  for (int mt = 0; mt < 4; mt++)
#pragma unroll
    for (int nt = 0; nt < 4; nt++)
#pragma unroll
      for (int r = 0; r < 4; r++) {
        int row = m0 + mw * 64 + mt * 16 + quad * 4 + r;
        int col = n0 + nw * 64 + nt * 16 + l16;
        C[(size_t)row * N + col] = (__bf16)(acc[mt][nt][r] * sc);
      }
}

// ---------- gemm_kv128: k = ckv@Wuk' (bx<8); vt = (ckv@Wuv')^T (bx>=8) ------
__global__ __launch_bounds__(256) void gemm_kv128(const __bf16* __restrict__ A,
                                                  const __bf16* __restrict__ Bk,
                                                  const __bf16* __restrict__ Bv,
                                                  __bf16* __restrict__ k,
                                                  __bf16* __restrict__ vt) {
  __shared__ __attribute__((aligned(16))) __bf16 Al[2][BUFE];
  __shared__ __attribute__((aligned(16))) __bf16 Bl[2][BUFE];
  __shared__ __attribute__((aligned(16))) __bf16 tw[4][64 * 72];
  int tid = threadIdx.x;
  int w = tid >> 6, lane = tid & 63;
  int quad = lane >> 4, l16 = lane & 15;
  int mw = w & 1, nw = w >> 1;
  int bx = blockIdx.x, m0 = blockIdx.y * 128;
  bool is_k = (bx < 8);
  const __bf16* Bt = is_k ? Bk : Bv;
  int n0 = (is_k ? bx : bx - 8) * 128;
  const int K = DLAT;
  int arow = w * 32 + (lane >> 2), acol = (lane & 3) << 3;

  floatx4 acc[4][4];
#pragma unroll
  for (int i = 0; i < 4; i++)
#pragma unroll
    for (int j = 0; j < 4; j++) acc[i][j] = (floatx4){0.f, 0.f, 0.f, 0.f};

  for (int k0 = 0; k0 < K; k0 += 64) {
#pragma unroll
    for (int kh = 0; kh < 2; kh++)
#pragma unroll
      for (int j = 0; j < 2; j++) {
        gload_lds16(A + (size_t)(m0 + arow + j * 16) * K + k0 + kh * 32 + acol,
                    &Al[kh][(w * 32 + j * 16) * 32]);
        gload_lds16(Bt + (size_t)(n0 + arow + j * 16) * K + k0 + kh * 32 + acol,
                    &Bl[kh][(w * 32 + j * 16) * 32]);
      }
    __syncthreads();
#pragma unroll
    for (int kh = 0; kh < 2; kh++) {
      bf16x8 af[4], bfr[4];
#pragma unroll
      for (int mt = 0; mt < 4; mt++)
        af[mt] =
            *(const bf16x8*)&Al[kh][(mw * 64 + mt * 16 + l16) * 32 + quad * 8];
#pragma unroll
      for (int nt = 0; nt < 4; nt++)
        bfr[nt] =
            *(const bf16x8*)&Bl[kh][(nw * 64 + nt * 16 + l16) * 32 + quad * 8];
#pragma unroll
      for (int mt = 0; mt < 4; mt++)
#pragma unroll
        for (int nt = 0; nt < 4; nt++)
          acc[mt][nt] = MFMA(af[mt], bfr[nt], acc[mt][nt]);
    }
    __syncthreads();
  }
  if (is_k) {
#pragma unroll
    for (int mt = 0; mt < 4; mt++)
#pragma unroll
      for (int nt = 0; nt < 4; nt++)
#pragma unroll
        for (int r = 0; r < 4; r++) {
          int row = m0 + mw * 64 + mt * 16 + quad * 4 + r;
          int col = n0 + nw * 64 + nt * 16 + l16;
          k[(size_t)row * DIMX + col] = (__bf16)acc[mt][nt][r];
        }
  } else {
#pragma unroll
    for (int mt = 0; mt < 4; mt++)
#pragma unroll
      for (int nt = 0; nt < 4; nt++)
#pragma unroll
        for (int r = 0; r < 4; r++)
          tw[w][(nt * 16 + l16) * 72 + mt * 16 + quad * 4 + r] =
              (__bf16)acc[mt][nt][r];
    int cbase = lane >> 3, chunk = lane & 7;
#pragma unroll
    for (int i = 0; i < 8; i++) {
      int c = cbase + i * 8;
      bf16x8 v8 = *(const bf16x8*)&tw[w][c * 72 + chunk * 8];
      *(bf16x8*)&vt[(size_t)(n0 + nw * 64 + c) * T_SEQ + m0 + mw * 64 +
                    chunk * 8] = v8;
    }
  }
}

// ---------- gemm_f128: out(f32) = ctx @ Wo' -------------------------------
__global__ __launch_bounds__(256) void gemm_f128(const __bf16* __restrict__ A,
                                                 const __bf16* __restrict__ Bt,
                                                 float* __restrict__ C) {
  __shared__ __attribute__((aligned(16))) __bf16 Al[2][BUFE];
  __shared__ __attribute__((aligned(16))) __bf16 Bl[2][BUFE];
  int tid = threadIdx.x;
  int w = tid >> 6, lane = tid & 63;
  int quad = lane >> 4, l16 = lane & 15;
  int mw = w & 1, nw = w >> 1;
  int n0 = blockIdx.x * 128, m0 = blockIdx.y * 128;
  const int K = DIMX, N = DIMX;
  int arow = w * 32 + (lane >> 2), acol = (lane & 3) << 3;

  floatx4 acc[4][4];
#pragma unroll
  for (int i = 0; i < 4; i++)
#pragma unroll
    for (int j = 0; j < 4; j++) acc[i][j] = (floatx4){0.f, 0.f, 0.f, 0.f};

  for (int k0 = 0; k0 < K; k0 += 64) {
#pragma unroll
    for (int kh = 0; kh < 2; kh++)
#pragma unroll
      for (int j = 0; j < 2; j++) {
        gload_lds16(A + (size_t)(m0 + arow + j * 16) * K + k0 + kh * 32 + acol,
                    &Al[kh][(w * 32 + j * 16) * 32]);
        gload_lds16(Bt + (size_t)(n0 + arow + j * 16) * K + k0 + kh * 32 + acol,
                    &Bl[kh][(w * 32 + j * 16) * 32]);
      }
    __syncthreads();
#pragma unroll
    for (int kh = 0; kh < 2; kh++) {
      bf16x8 af[4], bfr[4];
#pragma unroll
      for (int mt = 0; mt < 4; mt++)
        af[mt] =
            *(const bf16x8*)&Al[kh][(mw * 64 + mt * 16 + l16) * 32 + quad * 8];
#pragma unroll
      for (int nt = 0; nt < 4; nt++)
        bfr[nt] =
            *(const bf16x8*)&Bl[kh][(nw * 64 + nt * 16 + l16) * 32 + quad * 8];
#pragma unroll
      for (int mt = 0; mt < 4; mt++)
#pragma unroll
        for (int nt = 0; nt < 4; nt++)
          acc[mt][nt] = MFMA(af[mt], bfr[nt], acc[mt][nt]);
    }
    __syncthreads();
  }
#pragma unroll
  for (int mt = 0; mt < 4; mt++)
#pragma unroll
    for (int nt = 0; nt < 4; nt++)
#pragma unroll
      for (int r = 0; r < 4; r++) {
        int row = m0 + mw * 64 + mt * 16 + quad * 4 + r;
        int col = n0 + nw * 64 + nt * 16 + l16;
        C[(size_t)row * N + col] = acc[mt][nt][r];
      }
}

// ---------- flash attention (round-8 attn5, 84us validated) -----------------
#define PST 72
__global__ __launch_bounds__(512, 4) void mla_attn5(const __bf16* __restrict__ Q,
                                                    const __bf16* __restrict__ Kg,
                                                    const __bf16* __restrict__ Vt,
                                                    __bf16* __restrict__ ctx) {
  __shared__ __attribute__((aligned(16))) __bf16 Kl[2][64 * 64];
  __shared__ __attribute__((aligned(16))) __bf16 Vl[2][64 * 64];
  __shared__ __attribute__((aligned(16))) __bf16 Pl[128 * PST];
  int tid = threadIdx.x;
  int wave = tid >> 6, lane = tid & 63;
  int quad = lane >> 4, l16 = lane & 15;
  int wq = wave & 3;
  bool isA = (wave < 4);
  int h = blockIdx.y;
  int qa = (h & 8) ? (31 - blockIdx.x) : blockIdx.x;
  int qb = 63 - qa;
  int myqt = isA ? qa : qb;
  int myq0 = myqt * 64;
  int srow = tid >> 3, pos = tid & 7;
  int gco = pos << 3;
  int sw = ((pos ^ (srow & 7)) << 3);
  int swr = srow * 64 + sw;

  *(bf16x8*)&Pl[srow * PST + gco] =
      *(const bf16x8*)&Q[(size_t)(qa * 64 + srow) * DIMX + h * HD + gco];
  *(bf16x8*)&Pl[(64 + srow) * PST + gco] =
      *(const bf16x8*)&Q[(size_t)(qb * 64 + srow) * DIMX + h * HD + gco];
  *(bf16x8*)&Kl[0][swr] =
      *(const bf16x8*)&Kg[(size_t)srow * DIMX + h * HD + gco];
  *(bf16x8*)&Vl[0][swr] =
      *(const bf16x8*)&Vt[(size_t)(h * HD + srow) * T_SEQ + gco];
  __syncthreads();
  int fr = (wave * 16 + l16) * PST;
  bf16x8 qf0 = *(const bf16x8*)&Pl[fr + quad * 8];
  bf16x8 qf1 = *(const bf16x8*)&Pl[fr + 32 + quad * 8];

  int c0s = ((quad ^ (l16 & 7)) << 3);
  int c1s = (((4 + quad) ^ (l16 & 7)) << 3);

  floatx4 o[4];
  float l_i[4];
#pragma unroll
  for (int i = 0; i < 4; i++) {
    o[i] = (floatx4){0.f, 0.f, 0.f, 0.f};
    l_i[i] = 0.f;
  }

  for (int kt = 0; kt <= qb; kt++) {
    int cur = kt & 1, nxt = cur ^ 1;
    bool pre = (kt < qb);
    bf16x8 kpre, vpre;
    if (pre) {
      int k0n = (kt + 1) * 64;
      kpre = *(const bf16x8*)&Kg[(size_t)(k0n + srow) * DIMX + h * HD + gco];
      vpre = *(const bf16x8*)&Vt[(size_t)(h * HD + srow) * T_SEQ + k0n + gco];
    }
    if (!isA || kt <= qa) {
      const __bf16* Kc = Kl[cur];
      const __bf16* Vc = Vl[cur];
      floatx4 s[4];
#pragma unroll
      for (int ct = 0; ct < 4; ct++) {
        int rb = (ct * 16 + l16) * 64;
        bf16x8 kf0 = *(const bf16x8*)&Kc[rb + c0s];
        bf16x8 kf1 = *(const bf16x8*)&Kc[rb + c1s];
        floatx4 z = (floatx4){0.f, 0.f, 0.f, 0.f};
        z = MFMA(qf0, kf0, z);
        z = MFMA(qf1, kf1, z);
        s[ct] = z;
      }
      bool diag = (kt == myqt);
#pragma unroll
      for (int ct = 0; ct < 4; ct++)
#pragma unroll
        for (int r = 0; r < 4; r++) {
          float p = __expf(s[ct][r]);
          if (diag && (ct * 16 + l16 > wq * 16 + quad * 4 + r)) p = 0.f;
          l_i[r] += p;
          Pl[(wave * 16 + quad * 4 + r) * PST + ct * 16 + l16] = (__bf16)p;
        }
      bf16x8 pf0 = *(const bf16x8*)&Pl[fr + quad * 8];
      bf16x8 pf1 = *(const bf16x8*)&Pl[fr + 32 + quad * 8];
#pragma unroll
      for (int dt = 0; dt < 4; dt++) {
        int rb = (dt * 16 + l16) * 64;
        bf16x8 vf0 = *(const bf16x8*)&Vc[rb + c0s];
        bf16x8 vf1 = *(const bf16x8*)&Vc[rb + c1s];
        o[dt] = MFMA(pf0, vf0, o[dt]);
        o[dt] = MFMA(pf1, vf1, o[dt]);
      }
    }
    if (pre) {
      *(bf16x8*)&Kl[nxt][swr] = kpre;
      *(bf16x8*)&Vl[nxt][swr] = vpre;
    }
    __syncthreads();
  }

#pragma unroll
  for (int off = 1; off < 16; off <<= 1)
#pragma unroll
    for (int r = 0; r < 4; r++) l_i[r] += __shfl_xor(l_i[r], off, 64);

#pragma unroll
  for (int dt = 0; dt < 4; dt++)
#pragma unroll
    for (int r = 0; r < 4; r++) {
      float val = o[dt][r] / l_i[r];
      int row = myq0 + wq * 16 + quad * 4 + r;
      int col = h * HD + dt * 16 + l16;
      ctx[(size_t)row * DIMX + col] = (__bf16)val;
    }
}

extern "C" void kernel_launch(void* const* d_in, const int* in_sizes, int n_in,
                              void* d_out, int out_size, void* d_ws,
                              size_t ws_size, hipStream_t stream) {
  const float* x = (const float*)d_in[0];
  const float* wdkv = (const float*)d_in[1];
  const float* wuk = (const float*)d_in[2];
  const float* wuv = (const float*)d_in[3];
  const float* wuq = (const float*)d_in[4];
  const float* wo = (const float*)d_in[5];
  float* out = (float*)d_out;

  __bf16* ws = (__bf16*)d_ws;
  __bf16* x_bf = ws;                               // T*D
  __bf16* q = x_bf + (size_t)T_SEQ * DIMX;         // T*D (pre-scaled by 1/8)
  __bf16* k = q + (size_t)T_SEQ * DIMX;            // T*D
  __bf16* vt = k + (size_t)T_SEQ * DIMX;           // D*T
  __bf16* ctx = vt + (size_t)T_SEQ * DIMX;         // T*D
  __bf16* ckv = ctx + (size_t)T_SEQ * DIMX;        // T*DLAT
  __bf16* wt_dkv = ckv + (size_t)T_SEQ * DLAT;     // DLAT x DIM
  __bf16* wt_uk = wt_dkv + (size_t)DLAT * DIMX;    // DIM x DLAT
  __bf16* wt_uv = wt_uk + (size_t)DIMX * DLAT;     // DIM x DLAT
  __bf16* wt_uq = wt_uv + (size_t)DIMX * DLAT;     // DIM x DIM
  __bf16* wt_o = wt_uq + (size_t)DIMX * DIMX;      // DIM x DIM

  dim3 blk(256);
  prep_kernel<<<dim3(2752), blk, 0, stream>>>(x, wdkv, wuk, wuv, wuq, wo, x_bf,
                                              wt_dkv, wt_uk, wt_uv, wt_uq, wt_o);
  gemm_a128<<<dim3(10, T_SEQ / 128), blk, 0, stream>>>(x_bf, wt_dkv, wt_uq,
                                                       ckv, q);
  gemm_kv128<<<dim3(16, T_SEQ / 128), blk, 0, stream>>>(ckv, wt_uk, wt_uv, k,
                                                        vt);
  mla_attn5<<<dim3(32, NH), dim3(512), 0, stream>>>(q, k, vt, ctx);
  gemm_f128<<<dim3(DIMX / 128, T_SEQ / 128), blk, 0, stream>>>(ctx, wt_o, out);
}